// Round 1
// baseline (219.923 us; speedup 1.0000x reference)
//
#include <hip/hip_runtime.h>

// MultiScaleRoIAlign: B=2, Nb=256 (R=512 rois), C=256, PH=PW=7, GRID=2.
// R5: LDS-pipe attack. Previous version was ~70% LDS-pipe-bound (hand count:
// 16.4k ds_b32 instrs/CU * 5.8cyc + 20k conflict cyc ~= 115k of 165k cyc/CU).
//   (a) channel-interleaved float4 slab: ds_read_b128/ds_write_b128 move 4
//       channels per instruction -> 4x fewer DS instrs.
//   (b) psize-adaptive staging: kmax = ceil(psize/64) uniform groups instead
//       of always staging 1024 clamped elements (~2-3x fewer staging ops).
//   (c) 1-wave (64-thread) blocks so one 16 KB slab serves the whole block;
//       LDS caps residency at 10 blocks/CU; next-round register prefetch
//       (issued after the barrier) overlaps global latency with compute.

#define PHW 49
#define NCHUNK 8
#define CH 32            // channels per block (8 rounds of 4)
#define PSIZE 1024       // float4 slots per slab; psize provably <= ~900

__global__ __launch_bounds__(64) void msroi_kernel(
    const float* __restrict__ f0, const float* __restrict__ f1,
    const float* __restrict__ f2, const float* __restrict__ f3,
    const float* __restrict__ boxes, float* __restrict__ out)
{
    const int C = 256, Nb = 256;
    const int r = blockIdx.x;            // roi 0..511
    const int chunk = blockIdx.y;        // 0..7
    const int tid = threadIdx.x;         // 0..63, exactly one wave
    const int b = r / Nb;

    // ---- per-roi params (uniform) ----
    const float x1b = boxes[r * 4 + 0];
    const float y1b = boxes[r * 4 + 1];
    const float x2b = boxes[r * 4 + 2];
    const float y2b = boxes[r * 4 + 3];
    const float area = fmaxf((x2b - x1b) * (y2b - y1b), 0.0f);
    const float s = sqrtf(area);
    float lv = floorf(4.0f + log2f(s / 224.0f + 1e-6f));
    lv = fminf(fmaxf(lv, 2.0f), 5.0f);
    const int lvl = (int)lv - 2;

    const float* feat;
    int H, W;
    float scale;
    switch (lvl) {
        case 0:  feat = f0; H = 200; W = 200; scale = 0.25f;    break;
        case 1:  feat = f1; H = 100; W = 100; scale = 0.125f;   break;
        case 2:  feat = f2; H = 50;  W = 50;  scale = 0.0625f;  break;
        default: feat = f3; H = 25;  W = 25;  scale = 0.03125f; break;
    }
    const int HW = H * W;

    const float x1 = x1b * scale, y1 = y1b * scale;
    const float x2 = x2b * scale, y2 = y2b * scale;
    const float roi_w = fmaxf(x2 - x1, 1.0f);
    const float roi_h = fmaxf(y2 - y1, 1.0f);
    const float bin_w = roi_w * (1.0f / 7.0f);
    const float bin_h = roi_h * (1.0f / 7.0f);

    // ---- patch bounds (uniform): samples at gy,gx in {0.25 .. 6.75} ----
    const float ys0 = fminf(fmaxf(y1 + 0.25f * bin_h, 0.0f), (float)(H - 1));
    const float ys1 = fminf(fmaxf(y1 + 6.75f * bin_h, 0.0f), (float)(H - 1));
    const float xs0 = fminf(fmaxf(x1 + 0.25f * bin_w, 0.0f), (float)(W - 1));
    const float xs1 = fminf(fmaxf(x1 + 6.75f * bin_w, 0.0f), (float)(W - 1));
    const int row0 = (int)floorf(ys0);
    const int row1 = min((int)floorf(ys1) + 1, H - 1);
    const int col0 = (int)floorf(xs0);
    const int col1 = min((int)floorf(xs1) + 1, W - 1);
    const int prows = row1 - row0 + 1;
    const int pcols = col1 - col0 + 1;
    const int psize = prows * pcols;
    const int wstride = W - pcols;                 // row jump in global plane
    const float inv_pcols = 1.0f / (float)pcols;

    // ---- per-thread staging offsets (loop-invariant): e = tid + k*64 ----
    int goff[16];
#pragma unroll
    for (int k = 0; k < 16; ++k) {
        const int e = tid + k * 64;
        const int ec = min(e, psize - 1);
        const int rr = (int)floorf(((float)ec + 0.5f) * inv_pcols);
        goff[k] = ec + rr * wstride;
    }
    const int kmax = (psize + 63) >> 6;            // 1..16, block-uniform

    // ---- per-lane bin descriptors (patch-relative, channel-invariant) ----
    const int bin = tid;                 // lanes >=49 idle in compute
    const bool active = bin < PHW;
    int   offs[16];
    float wts[16];
    {
        const int bb = active ? bin : 0;
        const int ph = bb / 7;
        const int pw = bb - ph * 7;
#pragma unroll
        for (int g = 0; g < 4; ++g) {
            const int iy = g >> 1, ix = g & 1;
            const float gy = (float)ph + ((float)iy + 0.5f) * 0.5f;
            const float gx = (float)pw + ((float)ix + 0.5f) * 0.5f;
            const float y = y1 + gy * bin_h;
            const float x = x1 + gx * bin_w;
            const bool valid = (y >= -1.0f) && (y <= (float)H) &&
                               (x >= -1.0f) && (x <= (float)W);
            const float yc = fminf(fmaxf(y, 0.0f), (float)(H - 1));
            const float xc = fminf(fmaxf(x, 0.0f), (float)(W - 1));
            const int yl = (int)floorf(yc);
            const int xl = (int)floorf(xc);
            const int yh = min(yl + 1, H - 1);
            const int xh = min(xl + 1, W - 1);
            const float ly = yc - (float)yl;
            const float lx = xc - (float)xl;
            const float hy = 1.0f - ly, hx = 1.0f - lx;
            const float m = valid ? 0.25f : 0.0f;
            const int ry0 = (yl - row0) * pcols, ry1 = (yh - row0) * pcols;
            const int cx0 = xl - col0, cx1 = xh - col0;
            offs[g * 4 + 0] = ry0 + cx0;  wts[g * 4 + 0] = hy * hx * m;
            offs[g * 4 + 1] = ry0 + cx1;  wts[g * 4 + 1] = hy * lx * m;
            offs[g * 4 + 2] = ry1 + cx0;  wts[g * 4 + 2] = ly * hx * m;
            offs[g * 4 + 3] = ry1 + cx1;  wts[g * 4 + 3] = ly * lx * m;
        }
    }

    // ---- channel-interleaved slab: lds4[e] = {c0[e], c1[e], c2[e], c3[e]} ----
    __shared__ float4 lds4[PSIZE];       // 16 KB -> 10 blocks/CU

    const int cbase = chunk * CH;
    const float* __restrict__ fch =
        feat + (size_t)(b * C + cbase) * HW + (row0 * W + col0);
    float* __restrict__ outp =
        out + (size_t)r * C * PHW + (size_t)cbase * PHW + bin;

    float4 buf[16];                      // statically indexed -> registers

#define LOADR(CCV)                                                         \
    do {                                                                   \
        const float* __restrict__ g0 = fch + (size_t)((CCV) + 0) * HW;     \
        const float* __restrict__ g1 = fch + (size_t)((CCV) + 1) * HW;     \
        const float* __restrict__ g2 = fch + (size_t)((CCV) + 2) * HW;     \
        const float* __restrict__ g3 = fch + (size_t)((CCV) + 3) * HW;     \
        _Pragma("unroll")                                                  \
        for (int k = 0; k < 16; ++k) {                                     \
            if (k < kmax) {  /* uniform branch: skip clamped groups */     \
                buf[k].x = g0[goff[k]];                                    \
                buf[k].y = g1[goff[k]];                                    \
                buf[k].z = g2[goff[k]];                                    \
                buf[k].w = g3[goff[k]];                                    \
            }                                                              \
        }                                                                  \
    } while (0)

    LOADR(0);
    for (int cc = 0; cc < CH; cc += 4) {
        __syncthreads();   // prev round's LDS reads done (cheap: 1 wave)
#pragma unroll
        for (int k = 0; k < 16; ++k)
            if (k < kmax) lds4[tid + k * 64] = buf[k];   // ds_write_b128
        __syncthreads();   // staged data visible

        if (cc + 4 < CH) LOADR(cc + 4);  // prefetch next round; overlaps compute

        if (active) {
            float4 acc = make_float4(0.0f, 0.0f, 0.0f, 0.0f);
#pragma unroll
            for (int j = 0; j < 16; ++j) {
                const float4 v = lds4[offs[j]];          // ds_read_b128: 4 ch/instr
                acc.x += wts[j] * v.x;
                acc.y += wts[j] * v.y;
                acc.z += wts[j] * v.z;
                acc.w += wts[j] * v.w;
            }
            outp[(size_t)(cc + 0) * PHW] = acc.x;
            outp[(size_t)(cc + 1) * PHW] = acc.y;
            outp[(size_t)(cc + 2) * PHW] = acc.z;
            outp[(size_t)(cc + 3) * PHW] = acc.w;
        }
    }
#undef LOADR
}

extern "C" void kernel_launch(void* const* d_in, const int* in_sizes, int n_in,
                              void* d_out, int out_size, void* d_ws, size_t ws_size,
                              hipStream_t stream) {
    const float* f0 = (const float*)d_in[0];
    const float* f1 = (const float*)d_in[1];
    const float* f2 = (const float*)d_in[2];
    const float* f3 = (const float*)d_in[3];
    const float* boxes = (const float*)d_in[4];
    float* out = (float*)d_out;

    const int R = in_sizes[4] / 4;   // 512 rois
    dim3 grid(R, NCHUNK);
    msroi_kernel<<<grid, 64, 0, stream>>>(f0, f1, f2, f3, boxes, out);
}

// Round 2
// 180.799 us; speedup vs baseline: 1.2164x; 1.2164x over previous
//
#include <hip/hip_runtime.h>

// MultiScaleRoIAlign: B=2, Nb=256 (R=512 rois), C=256, PH=PW=7, GRID=2.
// R6: float4 slab (R5's DS-instr diet: b128 ops, 4 ch/instr) restored to
// 256-thread blocks (R4's occupancy). R5 post-mortem: DS work fell 4x but
// 1-wave blocks + VGPR=120 collapsed occupancy to 13% -> latency-bound.
//   - staging: all 256 threads, e = tid + k*256, kmax = ceil(psize/256) <= 4,
//     prefetch buf[4] float4 = 16 VGPRs (not 64).
//   - compute: thread = bin*4 + q; quad lane q does sample q's 4 taps
//     (4 x ds_read_b128), 8-shuffle quad butterfly, lane q writes ch cc+q.
//   - 16 KB LDS -> up to 10 blocks/CU; wave cap 8 blocks; 2 barriers/round.

#define PHW 49
#define NCHUNK 8
#define CH 32            // channels per block (8 rounds of 4)
#define PSIZE 1024       // float4 slots; psize provably <= ~900

__global__ __launch_bounds__(256) void msroi_kernel(
    const float* __restrict__ f0, const float* __restrict__ f1,
    const float* __restrict__ f2, const float* __restrict__ f3,
    const float* __restrict__ boxes, float* __restrict__ out)
{
    const int C = 256, Nb = 256;
    const int r = blockIdx.x;            // roi 0..511
    const int chunk = blockIdx.y;        // 0..7
    const int tid = threadIdx.x;         // 0..255
    const int b = r / Nb;

    const int bin = tid >> 2;            // 0..63 (active if < 49)
    const int q   = tid & 3;             // 2x2 sample index within bin
    const bool active = bin < PHW;

    // ---- per-roi params (uniform) ----
    const float x1b = boxes[r * 4 + 0];
    const float y1b = boxes[r * 4 + 1];
    const float x2b = boxes[r * 4 + 2];
    const float y2b = boxes[r * 4 + 3];
    const float area = fmaxf((x2b - x1b) * (y2b - y1b), 0.0f);
    const float s = sqrtf(area);
    float lv = floorf(4.0f + log2f(s / 224.0f + 1e-6f));
    lv = fminf(fmaxf(lv, 2.0f), 5.0f);
    const int lvl = (int)lv - 2;

    const float* feat;
    int H, W;
    float scale;
    switch (lvl) {
        case 0:  feat = f0; H = 200; W = 200; scale = 0.25f;    break;
        case 1:  feat = f1; H = 100; W = 100; scale = 0.125f;   break;
        case 2:  feat = f2; H = 50;  W = 50;  scale = 0.0625f;  break;
        default: feat = f3; H = 25;  W = 25;  scale = 0.03125f; break;
    }
    const int HW = H * W;

    const float x1 = x1b * scale, y1 = y1b * scale;
    const float x2 = x2b * scale, y2 = y2b * scale;
    const float roi_w = fmaxf(x2 - x1, 1.0f);
    const float roi_h = fmaxf(y2 - y1, 1.0f);
    const float bin_w = roi_w * (1.0f / 7.0f);
    const float bin_h = roi_h * (1.0f / 7.0f);

    // ---- patch bounds (uniform): samples at gy,gx in {0.25 .. 6.75} ----
    const float ys0 = fminf(fmaxf(y1 + 0.25f * bin_h, 0.0f), (float)(H - 1));
    const float ys1 = fminf(fmaxf(y1 + 6.75f * bin_h, 0.0f), (float)(H - 1));
    const float xs0 = fminf(fmaxf(x1 + 0.25f * bin_w, 0.0f), (float)(W - 1));
    const float xs1 = fminf(fmaxf(x1 + 6.75f * bin_w, 0.0f), (float)(W - 1));
    const int row0 = (int)floorf(ys0);
    const int row1 = min((int)floorf(ys1) + 1, H - 1);
    const int col0 = (int)floorf(xs0);
    const int col1 = min((int)floorf(xs1) + 1, W - 1);
    const int prows = row1 - row0 + 1;
    const int pcols = col1 - col0 + 1;
    const int psize = prows * pcols;
    const int wstride = W - pcols;                 // row jump in global plane
    const float inv_pcols = 1.0f / (float)pcols;

    // ---- per-thread staging offsets (loop-invariant): e = tid + k*256 ----
    int goff[4];
#pragma unroll
    for (int k = 0; k < 4; ++k) {
        const int e = tid + k * 256;
        const int ec = min(e, psize - 1);
        const int rr = (int)floorf(((float)ec + 0.5f) * inv_pcols);
        goff[k] = ec + rr * wstride;
    }
    const int kmax = (psize + 255) >> 8;           // 1..4, block-uniform

    // ---- per-lane tap descriptors: sample q of bin -> 4 bilinear taps ----
    int   offs[4];
    float wts[4];
    {
        const int bb = active ? bin : 0;
        const int ph = bb / 7;
        const int pw = bb - ph * 7;
        const int iy = q >> 1, ix = q & 1;
        const float gy = (float)ph + ((float)iy + 0.5f) * 0.5f;
        const float gx = (float)pw + ((float)ix + 0.5f) * 0.5f;
        const float y = y1 + gy * bin_h;
        const float x = x1 + gx * bin_w;
        const bool valid = (y >= -1.0f) && (y <= (float)H) &&
                           (x >= -1.0f) && (x <= (float)W);
        const float yc = fminf(fmaxf(y, 0.0f), (float)(H - 1));
        const float xc = fminf(fmaxf(x, 0.0f), (float)(W - 1));
        const int yl = (int)floorf(yc);
        const int xl = (int)floorf(xc);
        const int yh = min(yl + 1, H - 1);
        const int xh = min(xl + 1, W - 1);
        const float ly = yc - (float)yl;
        const float lx = xc - (float)xl;
        const float hy = 1.0f - ly, hx = 1.0f - lx;
        const float m = valid ? 0.25f : 0.0f;
        const int ry0 = (yl - row0) * pcols, ry1 = (yh - row0) * pcols;
        const int cx0 = xl - col0, cx1 = xh - col0;
        offs[0] = ry0 + cx0;  wts[0] = hy * hx * m;
        offs[1] = ry0 + cx1;  wts[1] = hy * lx * m;
        offs[2] = ry1 + cx0;  wts[2] = ly * hx * m;
        offs[3] = ry1 + cx1;  wts[3] = ly * lx * m;
    }

    // ---- channel-interleaved slab: lds4[e] = {c0[e], c1[e], c2[e], c3[e]} ----
    __shared__ float4 lds4[PSIZE];       // 16 KB

    const int cbase = chunk * CH;
    const float* __restrict__ fch =
        feat + (size_t)(b * C + cbase) * HW + (row0 * W + col0);
    float* __restrict__ outp =
        out + (size_t)r * C * PHW + (size_t)cbase * PHW;

    float4 buf[4];                       // statically indexed -> registers

#define LOADR(CCV)                                                         \
    do {                                                                   \
        const float* __restrict__ g0 = fch + (size_t)((CCV) + 0) * HW;     \
        const float* __restrict__ g1 = fch + (size_t)((CCV) + 1) * HW;     \
        const float* __restrict__ g2 = fch + (size_t)((CCV) + 2) * HW;     \
        const float* __restrict__ g3 = fch + (size_t)((CCV) + 3) * HW;     \
        _Pragma("unroll")                                                  \
        for (int k = 0; k < 4; ++k) {                                      \
            if (k < kmax) {  /* uniform branch: skip clamped groups */     \
                buf[k].x = g0[goff[k]];                                    \
                buf[k].y = g1[goff[k]];                                    \
                buf[k].z = g2[goff[k]];                                    \
                buf[k].w = g3[goff[k]];                                    \
            }                                                              \
        }                                                                  \
    } while (0)

    LOADR(0);
    for (int cc = 0; cc < CH; cc += 4) {
        __syncthreads();   // prev round's LDS reads complete (WAR)
#pragma unroll
        for (int k = 0; k < 4; ++k)
            if (k < kmax) lds4[tid + k * 256] = buf[k];   // ds_write_b128
        __syncthreads();   // staged data visible

        if (cc + 4 < CH) LOADR(cc + 4);  // prefetch next round under compute

        if (active) {
            float4 a = make_float4(0.0f, 0.0f, 0.0f, 0.0f);
#pragma unroll
            for (int j = 0; j < 4; ++j) {
                const float4 v = lds4[offs[j]];          // ds_read_b128
                a.x += wts[j] * v.x;
                a.y += wts[j] * v.y;
                a.z += wts[j] * v.z;
                a.w += wts[j] * v.w;
            }
            // quad butterfly: sum the 4 samples (masks 1,2 stay in-quad)
            a.x += __shfl_xor(a.x, 1); a.y += __shfl_xor(a.y, 1);
            a.z += __shfl_xor(a.z, 1); a.w += __shfl_xor(a.w, 1);
            a.x += __shfl_xor(a.x, 2); a.y += __shfl_xor(a.y, 2);
            a.z += __shfl_xor(a.z, 2); a.w += __shfl_xor(a.w, 2);
            // lane q writes channel cc+q at this bin
            const float vout = (q == 0) ? a.x : (q == 1) ? a.y
                             : (q == 2) ? a.z : a.w;
            outp[(size_t)(cc + q) * PHW + bin] = vout;
        }
    }
#undef LOADR
}

extern "C" void kernel_launch(void* const* d_in, const int* in_sizes, int n_in,
                              void* d_out, int out_size, void* d_ws, size_t ws_size,
                              hipStream_t stream) {
    const float* f0 = (const float*)d_in[0];
    const float* f1 = (const float*)d_in[1];
    const float* f2 = (const float*)d_in[2];
    const float* f3 = (const float*)d_in[3];
    const float* boxes = (const float*)d_in[4];
    float* out = (float*)d_out;

    const int R = in_sizes[4] / 4;   // 512 rois
    dim3 grid(R, NCHUNK);
    msroi_kernel<<<grid, 256, 0, stream>>>(f0, f1, f2, f3, boxes, out);
}